// Round 9
// baseline (422.489 us; speedup 1.0000x reference)
//
#include <hip/hip_runtime.h>
#include <math.h>

#define HW 4096
#define CCH 256
#define DQK 32
#define QB 64
#define JB 64
#define NT2 (HW / 2 / JB)   // 32 j-tiles per half-block

typedef __attribute__((ext_vector_type(8))) short bf16x8;
typedef __attribute__((ext_vector_type(4))) float f32x4;

__device__ __forceinline__ ushort f2bf(float f) {
    union { float f; unsigned u; } v; v.f = f;
    unsigned u = v.u;
    unsigned r = u + 0x7fffu + ((u >> 16) & 1u);   // round-to-nearest-even
    return (ushort)(r >> 16);
}
__device__ __forceinline__ float bf2f(ushort h) {
    union { unsigned u; float f; } v; v.u = ((unsigned)h) << 16;
    return v.f;
}

// ---------------------------------------------------------------------------
// K0: x (fp32) -> xbf (bf16), same [B][C][HW] layout.
// ---------------------------------------------------------------------------
__global__ __launch_bounds__(256) void x2bf_kernel(
    const float* __restrict__ x, ushort* __restrict__ xbf)
{
    size_t i = ((size_t)blockIdx.x * 256 + threadIdx.x) * 4;
    float4 v = *(const float4*)(x + i);
    ushort4 o = make_ushort4(f2bf(v.x), f2bf(v.y), f2bf(v.z), f2bf(v.w));
    *(ushort4*)(xbf + i) = o;
}

// ---------------------------------------------------------------------------
// K1: qT/kT in hi+lo bf16, layout [B*HW][32].
// ---------------------------------------------------------------------------
__global__ __launch_bounds__(256) void qkhl_kernel(
    const float* __restrict__ x,
    const float* __restrict__ Wq, const float* __restrict__ bq,
    const float* __restrict__ Wk, const float* __restrict__ bk,
    ushort* __restrict__ qth, ushort* __restrict__ qtl,
    ushort* __restrict__ kth, ushort* __restrict__ ktl)
{
    const float* W    = blockIdx.y ? Wk : Wq;
    const float* bias = blockIdx.y ? bk : bq;
    ushort* outh      = blockIdx.y ? kth : qth;
    ushort* outl      = blockIdx.y ? ktl : qtl;

    const int t  = threadIdx.x;
    const int p  = t & 63;
    const int cq = t >> 6;
    const int g0 = blockIdx.x * 64;
    const int b  = g0 >> 12;
    const int pp = (g0 & (HW - 1)) + p;
    const float* xb = x + (size_t)b * CCH * HW + pp;

    float acc[DQK];
#pragma unroll
    for (int o = 0; o < DQK; ++o) acc[o] = 0.f;

    for (int c0 = 64 * cq; c0 < 64 * cq + 64; c0 += 8) {
        float xv[8];
#pragma unroll
        for (int cc = 0; cc < 8; ++cc) xv[cc] = xb[(size_t)(c0 + cc) * HW];
#pragma unroll
        for (int o = 0; o < DQK; ++o)
#pragma unroll
            for (int cc = 0; cc < 8; ++cc)
                acc[o] = fmaf(W[o * CCH + c0 + cc], xv[cc], acc[o]);
    }

    __shared__ float red[4][64][DQK + 1];
#pragma unroll
    for (int o = 0; o < DQK; ++o) red[cq][p][o] = acc[o];
    __syncthreads();

    const int pr = t & 63;
    const int o8 = t >> 6;
    ushort hv[8], lv[8];
#pragma unroll
    for (int oo = 0; oo < 8; ++oo) {
        const int o = o8 * 8 + oo;
        float s = red[0][pr][o] + red[1][pr][o] + red[2][pr][o] + red[3][pr][o]
                + bias[o];
        ushort h = f2bf(s);
        hv[oo] = h;
        lv[oo] = f2bf(s - bf2f(h));
    }
    const size_t g = (size_t)(g0 + pr) * DQK + o8 * 8;
    *(ushort4*)(outh + g)     = make_ushort4(hv[0], hv[1], hv[2], hv[3]);
    *(ushort4*)(outh + g + 4) = make_ushort4(hv[4], hv[5], hv[6], hv[7]);
    *(ushort4*)(outl + g)     = make_ushort4(lv[0], lv[1], lv[2], lv[3]);
    *(ushort4*)(outl + g + 4) = make_ushort4(lv[4], lv[5], lv[6], lv[7]);
}

// ---------------------------------------------------------------------------
// K2: Wov = Wo x Wv (256x256) emitted as hi/lo bf16; bov = Wo bv + bo (fp32).
// ---------------------------------------------------------------------------
__global__ __launch_bounds__(256) void wov2_kernel(
    const float* __restrict__ Wo, const float* __restrict__ Wv,
    const float* __restrict__ bv, const float* __restrict__ bo,
    ushort* __restrict__ Wovh, ushort* __restrict__ Wovl,
    float* __restrict__ bov)
{
    int o = blockIdx.x;
    int c = threadIdx.x;
    float acc = 0.f;
#pragma unroll 8
    for (int m = 0; m < CCH; ++m)
        acc = fmaf(Wo[o * CCH + m], Wv[m * CCH + c], acc);
    ushort h = f2bf(acc);
    Wovh[o * CCH + c] = h;
    Wovl[o * CCH + c] = f2bf(acc - bf2f(h));

    __shared__ float red[256];
    red[c] = Wo[o * CCH + c] * bv[c];
    __syncthreads();
    for (int s = 128; s > 0; s >>= 1) {
        if (c < s) red[c] += red[c + s];
        __syncthreads();
    }
    if (c == 0) bov[o] = red[0] + bo[o];
}

// ---------------------------------------------------------------------------
// K3: split-j flash attention on x (V/O folded). 512 thr, grid 512 (2 blk/CU).
// Block n: b=(n&7)>>1, half=n&1 (j in [half*2048, +2048)), itile=n>>3.
// Per half: partial output po[half] (bf16, PIXEL-major [P][C]) + (m,l) per row
// for the flash combine in final3. Hi/lo MFMA scores, K-prefetch,
// wave-parallel softmax, XOR-swizzled P, one barrier/tile (all HW-validated).
// ---------------------------------------------------------------------------
__global__ __launch_bounds__(512, 4) void attn4_kernel(
    const ushort* __restrict__ qth, const ushort* __restrict__ qtl,
    const ushort* __restrict__ kth, const ushort* __restrict__ ktl,
    const ushort* __restrict__ xbf, const float* __restrict__ mask,
    ushort* __restrict__ po0, ushort* __restrict__ po1,
    float* __restrict__ ml)
{
    __shared__ __align__(16) ushort pbs[2][QB * JB];
    __shared__ float fs2[2][QB];
    __shared__ float lsb[QB];

    const int t    = threadIdx.x;
    const int w    = t >> 6;
    const int lane = t & 63;
    const int lm   = lane & 15;
    const int lg   = lane >> 4;
    const int ib   = w & 3;

    const int n    = blockIdx.x;
    const int b    = (n & 7) >> 1;
    const int half = n & 1;
    const int i0   = (n >> 3) * QB;
    const int J0   = half * (HW / 2);

    const ushort* xb = xbf  + (size_t)b * CCH * HW;
    const float*  mb = mask + (size_t)b * HW;

    bf16x8 qh, ql;
    {
        const size_t qr = ((size_t)(b * HW + i0 + 16 * ib + lm)) * DQK + 8 * lg;
        qh = *(const bf16x8*)(qth + qr);
        ql = *(const bf16x8*)(qtl + qr);
    }
    const float mi = mb[i0 + 16 * ib + lm];
    float mreg = -INFINITY, lreg = 0.f;

    f32x4 acc[2][4];
#pragma unroll
    for (int cf = 0; cf < 2; ++cf)
#pragma unroll
        for (int fi = 0; fi < 4; ++fi) acc[cf][fi] = (f32x4){0.f, 0.f, 0.f, 0.f};

    // preload K-frags for first tile of this half
    bf16x8 kh[4], kl[4];
    if (w < 4) {
#pragma unroll
        for (int mf = 0; mf < 4; ++mf) {
            const size_t kr = ((size_t)(b * HW + J0 + 16 * mf + lm)) * DQK + 8 * lg;
            kh[mf] = *(const bf16x8*)(kth + kr);
            kl[mf] = *(const bf16x8*)(ktl + kr);
        }
    }

    for (int jt = 0; jt < NT2; ++jt) {
        const int j0  = J0 + jt * JB;
        const int buf = jt & 1;

        bf16x8 afr[2][2];
#pragma unroll
        for (int cf = 0; cf < 2; ++cf)
#pragma unroll
            for (int ks = 0; ks < 2; ++ks)
                afr[cf][ks] = *(const bf16x8*)(xb +
                    (size_t)(32 * w + 16 * cf + lm) * HW + j0 + 32 * ks + 8 * lg);

        if (w < 4) {
            f32x4 sc[4];
#pragma unroll
            for (int mf = 0; mf < 4; ++mf) {
                f32x4 z = (f32x4){0.f, 0.f, 0.f, 0.f};
                z = __builtin_amdgcn_mfma_f32_16x16x32_bf16(kh[mf], qh, z, 0, 0, 0);
                z = __builtin_amdgcn_mfma_f32_16x16x32_bf16(kl[mf], qh, z, 0, 0, 0);
                z = __builtin_amdgcn_mfma_f32_16x16x32_bf16(kh[mf], ql, z, 0, 0, 0);
                sc[mf] = z;
            }
            const int jn = (jt + 1 < NT2) ? j0 + JB : j0;
#pragma unroll
            for (int mf = 0; mf < 4; ++mf) {
                const size_t kr = ((size_t)(b * HW + jn + 16 * mf + lm)) * DQK + 8 * lg;
                kh[mf] = *(const bf16x8*)(kth + kr);
                kl[mf] = *(const bf16x8*)(ktl + kr);
            }
            float pm = -INFINITY;
#pragma unroll
            for (int mf = 0; mf < 4; ++mf) {
                float4 mj = *(const float4*)&mb[j0 + 16 * mf + 4 * lg];
#pragma unroll
                for (int r = 0; r < 4; ++r) {
                    float mjr = (r == 0) ? mj.x : (r == 1) ? mj.y : (r == 2) ? mj.z : mj.w;
                    float mm = mi * mjr;
                    float v = (mm == 0.f) ? -INFINITY : sc[mf][r] * mm;
                    sc[mf][r] = v;
                    pm = fmaxf(pm, v);
                }
            }
            pm = fmaxf(pm, __shfl_xor(pm, 16));
            pm = fmaxf(pm, __shfl_xor(pm, 32));
            const float mnew = fmaxf(mreg, pm);
            const float fc   = __expf(mreg - mnew);
            float psum = 0.f;
            const int swz = (lm & 7) << 3;
#pragma unroll
            for (int mf = 0; mf < 4; ++mf) {
                float p0 = __expf(sc[mf][0] - mnew);
                float p1 = __expf(sc[mf][1] - mnew);
                float p2 = __expf(sc[mf][2] - mnew);
                float p3 = __expf(sc[mf][3] - mnew);
                psum += p0 + p1 + p2 + p3;
                *(ushort4*)&pbs[buf][(16 * ib + lm) * JB + ((16 * mf + 4 * lg) ^ swz)] =
                    make_ushort4(f2bf(p0), f2bf(p1), f2bf(p2), f2bf(p3));
            }
            psum += __shfl_xor(psum, 16);
            psum += __shfl_xor(psum, 32);
            lreg = lreg * fc + psum;
            mreg = mnew;
            if (lg == 0) fs2[buf][16 * ib + lm] = fc;
        }
        __syncthreads();

        float fcol[4];
#pragma unroll
        for (int fi = 0; fi < 4; ++fi) fcol[fi] = fs2[buf][16 * fi + lm];
#pragma unroll
        for (int cf = 0; cf < 2; ++cf)
#pragma unroll
            for (int fi = 0; fi < 4; ++fi) acc[cf][fi] *= fcol[fi];

#pragma unroll
        for (int fi = 0; fi < 4; ++fi)
#pragma unroll
            for (int ks = 0; ks < 2; ++ks) {
                bf16x8 bfr = *(const bf16x8*)&pbs[buf][(16 * fi + lm) * JB +
                                ((32 * ks + 8 * lg) ^ ((lm & 7) << 3))];
#pragma unroll
                for (int cf = 0; cf < 2; ++cf)
                    acc[cf][fi] = __builtin_amdgcn_mfma_f32_16x16x32_bf16(
                        afr[cf][ks], bfr, acc[cf][fi], 0, 0, 0);
            }
    }

    // epilogue: per-half (m,l) + normalized partial o in bf16, pixel-major
    if (w < 4 && lg == 0) {
        lsb[16 * ib + lm] = lreg;
        ((float2*)ml)[(size_t)half * (4 * HW) + (size_t)b * HW + i0 + 16 * ib + lm] =
            make_float2(mreg, lreg);
    }
    __syncthreads();
    ushort* po = half ? po1 : po0;
    float linv[4];
#pragma unroll
    for (int fi = 0; fi < 4; ++fi) linv[fi] = 1.f / lsb[16 * fi + lm];
#pragma unroll
    for (int cf = 0; cf < 2; ++cf)
#pragma unroll
        for (int fi = 0; fi < 4; ++fi) {
            const size_t P  = (size_t)b * HW + i0 + 16 * fi + lm;
            const int    c0 = 32 * w + 16 * cf + 4 * lg;
            ushort4 pk = make_ushort4(f2bf(acc[cf][fi][0] * linv[fi]),
                                      f2bf(acc[cf][fi][1] * linv[fi]),
                                      f2bf(acc[cf][fi][2] * linv[fi]),
                                      f2bf(acc[cf][fi][3] * linv[fi]));
            *(ushort4*)(po + (P << 8) + c0) = pk;
        }
}

// ---------------------------------------------------------------------------
// K4 (final3): flash-combine + MFMA epilogue GEMM + residual + LayerNorm.
// grid 512 x 256 thr (4 waves). Block = 32 pixels; wave w owns o in [64w,+64).
// D[m=o][n=p] = (Wovh+Wovl) x B,  B[p][c] = w1*o1 + w2*o2 (combined, bf16).
// ---------------------------------------------------------------------------
__global__ __launch_bounds__(256, 2) void final3_kernel(
    const ushort* __restrict__ po0, const ushort* __restrict__ po1,
    const float* __restrict__ ml,
    const ushort* __restrict__ Wovh, const ushort* __restrict__ Wovl,
    const float* __restrict__ bov, const float* __restrict__ x,
    const float* __restrict__ gamma, const float* __restrict__ ln_w,
    const float* __restrict__ ln_b, float* __restrict__ out)
{
    const int t    = threadIdx.x;
    const int lane = t & 63;
    const int w    = t >> 6;
    const int lm   = lane & 15;
    const int lg   = lane >> 4;
    const int g0   = blockIdx.x * 32;        // global pixel over B*HW
    const int b    = g0 >> 12;
    const int pin0 = g0 & (HW - 1);

    // flash-combine weights per owned pixel (pf = 0,1)
    float w1[2], w2[2];
#pragma unroll
    for (int pf = 0; pf < 2; ++pf) {
        const int P = g0 + 16 * pf + lm;
        float2 a = ((const float2*)ml)[P];
        float2 c = ((const float2*)ml)[4 * HW + P];
        float M  = fmaxf(a.x, c.x);
        float e1 = __expf(a.x - M) * a.y;
        float e2 = __expf(c.x - M) * c.y;
        float dn = e1 + e2;
        w1[pf] = e1 / dn;
        w2[pf] = e2 / dn;
    }

    f32x4 acc[4][2];
#pragma unroll
    for (int of = 0; of < 4; ++of)
#pragma unroll
        for (int pf = 0; pf < 2; ++pf) acc[of][pf] = (f32x4){0.f, 0.f, 0.f, 0.f};

    for (int ks = 0; ks < 8; ++ks) {
        bf16x8 ah[4], al[4];
#pragma unroll
        for (int of = 0; of < 4; ++of) {
            const size_t r = (size_t)(64 * w + 16 * of + lm) * CCH + 32 * ks + 8 * lg;
            ah[of] = *(const bf16x8*)(Wovh + r);
            al[of] = *(const bf16x8*)(Wovl + r);
        }
        bf16x8 bfrag[2];
#pragma unroll
        for (int pf = 0; pf < 2; ++pf) {
            const size_t rb = ((size_t)(g0 + 16 * pf + lm) << 8) + 32 * ks + 8 * lg;
            bf16x8 b1 = *(const bf16x8*)(po0 + rb);
            bf16x8 b2 = *(const bf16x8*)(po1 + rb);
#pragma unroll
            for (int e = 0; e < 8; ++e) {
                float f = w1[pf] * bf2f((ushort)b1[e]) + w2[pf] * bf2f((ushort)b2[e]);
                bfrag[pf][e] = (short)f2bf(f);
            }
        }
#pragma unroll
        for (int of = 0; of < 4; ++of)
#pragma unroll
            for (int pf = 0; pf < 2; ++pf) {
                acc[of][pf] = __builtin_amdgcn_mfma_f32_16x16x32_bf16(
                    ah[of], bfrag[pf], acc[of][pf], 0, 0, 0);
                acc[of][pf] = __builtin_amdgcn_mfma_f32_16x16x32_bf16(
                    al[of], bfrag[pf], acc[of][pf], 0, 0, 0);
            }
    }

    // residual + per-pixel LN partial sums (v kept in acc)
    const float gam = gamma[0];
    float s1[2] = {0.f, 0.f}, s2[2] = {0.f, 0.f};
#pragma unroll
    for (int of = 0; of < 4; ++of)
#pragma unroll
        for (int pf = 0; pf < 2; ++pf)
#pragma unroll
            for (int r = 0; r < 4; ++r) {
                const int o   = 64 * w + 16 * of + 4 * lg + r;
                const int pin = pin0 + 16 * pf + lm;
                float v = fmaf(gam, acc[of][pf][r] + bov[o],
                               x[((size_t)b * CCH + o) * HW + pin]);
                acc[of][pf][r] = v;
                s1[pf] += v;
                s2[pf] = fmaf(v, v, s2[pf]);
            }
#pragma unroll
    for (int pf = 0; pf < 2; ++pf) {
        s1[pf] += __shfl_xor(s1[pf], 16); s1[pf] += __shfl_xor(s1[pf], 32);
        s2[pf] += __shfl_xor(s2[pf], 16); s2[pf] += __shfl_xor(s2[pf], 32);
    }

    __shared__ float l1[4][2][16], l2[4][2][16];
    __shared__ float lmu[2][16], lrs[2][16];
    if (lg == 0) {
#pragma unroll
        for (int pf = 0; pf < 2; ++pf) {
            l1[w][pf][lm] = s1[pf];
            l2[w][pf][lm] = s2[pf];
        }
    }
    __syncthreads();
    if (t < 32) {
        const int pf = t >> 4, q = t & 15;
        float a  = l1[0][pf][q] + l1[1][pf][q] + l1[2][pf][q] + l1[3][pf][q];
        float qq = l2[0][pf][q] + l2[1][pf][q] + l2[2][pf][q] + l2[3][pf][q];
        float mu  = a * (1.f / CCH);
        float var = qq * (1.f / CCH) - mu * mu;
        lmu[pf][q] = mu;
        lrs[pf][q] = 1.f / sqrtf(var + 1e-5f);
    }
    __syncthreads();

#pragma unroll
    for (int of = 0; of < 4; ++of)
#pragma unroll
        for (int pf = 0; pf < 2; ++pf) {
            const float mu = lmu[pf][lm], rs = lrs[pf][lm];
#pragma unroll
            for (int r = 0; r < 4; ++r) {
                const int o   = 64 * w + 16 * of + 4 * lg + r;
                const int pin = pin0 + 16 * pf + lm;
                float v = (acc[of][pf][r] - mu) * rs * ln_w[o] + ln_b[o];
                out[((size_t)b * CCH + o) * HW + pin] = v;
            }
        }
}

// ---------------------------------------------------------------------------
extern "C" void kernel_launch(void* const* d_in, const int* in_sizes, int n_in,
                              void* d_out, int out_size, void* d_ws, size_t ws_size,
                              hipStream_t stream)
{
    const float* x     = (const float*)d_in[0];
    const float* mask  = (const float*)d_in[1];
    const float* Wq    = (const float*)d_in[2];
    const float* bq    = (const float*)d_in[3];
    const float* Wk    = (const float*)d_in[4];
    const float* bk    = (const float*)d_in[5];
    const float* Wv    = (const float*)d_in[6];
    const float* bv    = (const float*)d_in[7];
    const float* Wo    = (const float*)d_in[8];
    const float* bo    = (const float*)d_in[9];
    const float* gamma = (const float*)d_in[10];
    const float* ln_w  = (const float*)d_in[11];
    const float* ln_b  = (const float*)d_in[12];
    float* out = (float*)d_out;

    // ws layout (bytes):
    //   qth/qtl/kth/ktl: 4 x 1MB           @ 0
    //   po0, po1: bf16 [B*HW][256], 8MB ea @ 4MB
    //   ml: float2 [2][B*HW] = 256KB       @ 20MB
    //   Wovh/Wovl: 128KB each, bov 1KB     @ 20.25MB
    //   xbf: bf16 8MB                      @ ~20.5MB   (total ~28.5MB)
    ushort* qth  = (ushort*)d_ws;
    ushort* qtl  = qth + (size_t)4 * HW * DQK;
    ushort* kth  = qtl + (size_t)4 * HW * DQK;
    ushort* ktl  = kth + (size_t)4 * HW * DQK;
    ushort* po0  = ktl + (size_t)4 * HW * DQK;
    ushort* po1  = po0 + (size_t)4 * HW * CCH;
    float*  ml   = (float*)(po1 + (size_t)4 * HW * CCH);
    ushort* Wovh = (ushort*)(ml + (size_t)2 * 2 * 4 * HW);
    ushort* Wovl = Wovh + CCH * CCH;
    float*  bov  = (float*)(Wovl + CCH * CCH);
    ushort* xbf  = (ushort*)(bov + 256);

    x2bf_kernel<<<4096, 256, 0, stream>>>(x, xbf);
    qkhl_kernel<<<dim3(256, 2), 256, 0, stream>>>(x, Wq, bq, Wk, bk,
                                                  qth, qtl, kth, ktl);
    wov2_kernel<<<256, 256, 0, stream>>>(Wo, Wv, bv, bo, Wovh, Wovl, bov);
    attn4_kernel<<<512, 512, 0, stream>>>(qth, qtl, kth, ktl, xbf, mask,
                                          po0, po1, ml);
    final3_kernel<<<512, 256, 0, stream>>>(po0, po1, ml, Wovh, Wovl, bov, x,
                                           gamma, ln_w, ln_b, out);
}

// Round 10
// 389.165 us; speedup vs baseline: 1.0856x; 1.0856x over previous
//
#include <hip/hip_runtime.h>
#include <math.h>

#define HW 4096
#define CCH 256
#define DQK 32
#define QB 64
#define JB 64
#define NT2 (HW / 2 / JB)   // 32 j-tiles per half-block

typedef __attribute__((ext_vector_type(8))) short bf16x8;
typedef __attribute__((ext_vector_type(4))) float f32x4;

__device__ __forceinline__ ushort f2bf(float f) {
    union { float f; unsigned u; } v; v.f = f;
    unsigned u = v.u;
    unsigned r = u + 0x7fffu + ((u >> 16) & 1u);   // round-to-nearest-even
    return (ushort)(r >> 16);
}
__device__ __forceinline__ float bf2f(ushort h) {
    union { unsigned u; float f; } v; v.u = ((unsigned)h) << 16;
    return v.f;
}

// ---------------------------------------------------------------------------
// K0: x (fp32) -> xbf (bf16), same [B][C][HW] layout.
// ---------------------------------------------------------------------------
__global__ __launch_bounds__(256) void x2bf_kernel(
    const float* __restrict__ x, ushort* __restrict__ xbf)
{
    size_t i = ((size_t)blockIdx.x * 256 + threadIdx.x) * 4;
    float4 v = *(const float4*)(x + i);
    ushort4 o = make_ushort4(f2bf(v.x), f2bf(v.y), f2bf(v.z), f2bf(v.w));
    *(ushort4*)(xbf + i) = o;
}

// ---------------------------------------------------------------------------
// K1: qT/kT in hi+lo bf16, layout [B*HW][32].
// ---------------------------------------------------------------------------
__global__ __launch_bounds__(256) void qkhl_kernel(
    const float* __restrict__ x,
    const float* __restrict__ Wq, const float* __restrict__ bq,
    const float* __restrict__ Wk, const float* __restrict__ bk,
    ushort* __restrict__ qth, ushort* __restrict__ qtl,
    ushort* __restrict__ kth, ushort* __restrict__ ktl)
{
    const float* W    = blockIdx.y ? Wk : Wq;
    const float* bias = blockIdx.y ? bk : bq;
    ushort* outh      = blockIdx.y ? kth : qth;
    ushort* outl      = blockIdx.y ? ktl : qtl;

    const int t  = threadIdx.x;
    const int p  = t & 63;
    const int cq = t >> 6;
    const int g0 = blockIdx.x * 64;
    const int b  = g0 >> 12;
    const int pp = (g0 & (HW - 1)) + p;
    const float* xb = x + (size_t)b * CCH * HW + pp;

    float acc[DQK];
#pragma unroll
    for (int o = 0; o < DQK; ++o) acc[o] = 0.f;

    for (int c0 = 64 * cq; c0 < 64 * cq + 64; c0 += 8) {
        float xv[8];
#pragma unroll
        for (int cc = 0; cc < 8; ++cc) xv[cc] = xb[(size_t)(c0 + cc) * HW];
#pragma unroll
        for (int o = 0; o < DQK; ++o)
#pragma unroll
            for (int cc = 0; cc < 8; ++cc)
                acc[o] = fmaf(W[o * CCH + c0 + cc], xv[cc], acc[o]);
    }

    __shared__ float red[4][64][DQK + 1];
#pragma unroll
    for (int o = 0; o < DQK; ++o) red[cq][p][o] = acc[o];
    __syncthreads();

    const int pr = t & 63;
    const int o8 = t >> 6;
    ushort hv[8], lv[8];
#pragma unroll
    for (int oo = 0; oo < 8; ++oo) {
        const int o = o8 * 8 + oo;
        float s = red[0][pr][o] + red[1][pr][o] + red[2][pr][o] + red[3][pr][o]
                + bias[o];
        ushort h = f2bf(s);
        hv[oo] = h;
        lv[oo] = f2bf(s - bf2f(h));
    }
    const size_t g = (size_t)(g0 + pr) * DQK + o8 * 8;
    *(ushort4*)(outh + g)     = make_ushort4(hv[0], hv[1], hv[2], hv[3]);
    *(ushort4*)(outh + g + 4) = make_ushort4(hv[4], hv[5], hv[6], hv[7]);
    *(ushort4*)(outl + g)     = make_ushort4(lv[0], lv[1], lv[2], lv[3]);
    *(ushort4*)(outl + g + 4) = make_ushort4(lv[4], lv[5], lv[6], lv[7]);
}

// ---------------------------------------------------------------------------
// K2: Wov = Wo x Wv (256x256) emitted as hi/lo bf16; bov = Wo bv + bo (fp32).
// ---------------------------------------------------------------------------
__global__ __launch_bounds__(256) void wov2_kernel(
    const float* __restrict__ Wo, const float* __restrict__ Wv,
    const float* __restrict__ bv, const float* __restrict__ bo,
    ushort* __restrict__ Wovh, ushort* __restrict__ Wovl,
    float* __restrict__ bov)
{
    int o = blockIdx.x;
    int c = threadIdx.x;
    float acc = 0.f;
#pragma unroll 8
    for (int m = 0; m < CCH; ++m)
        acc = fmaf(Wo[o * CCH + m], Wv[m * CCH + c], acc);
    ushort h = f2bf(acc);
    Wovh[o * CCH + c] = h;
    Wovl[o * CCH + c] = f2bf(acc - bf2f(h));

    __shared__ float red[256];
    red[c] = Wo[o * CCH + c] * bv[c];
    __syncthreads();
    for (int s = 128; s > 0; s >>= 1) {
        if (c < s) red[c] += red[c + s];
        __syncthreads();
    }
    if (c == 0) bov[o] = red[0] + bo[o];
}

// ---------------------------------------------------------------------------
// K3: split-j flash attention on x (V/O folded). 512 thr, grid 512 (2 blk/CU).
// Epilogue writes po CHANNEL-major [b][c][HW] (bf16) — the validated attn3
// coalesced store pattern (round 9's pixel-major po caused 25x HBM write
// amplification: WRITE_SIZE 420 MB, 1.78 TB/s store-bound).
// ---------------------------------------------------------------------------
__global__ __launch_bounds__(512, 4) void attn4_kernel(
    const ushort* __restrict__ qth, const ushort* __restrict__ qtl,
    const ushort* __restrict__ kth, const ushort* __restrict__ ktl,
    const ushort* __restrict__ xbf, const float* __restrict__ mask,
    ushort* __restrict__ po0, ushort* __restrict__ po1,
    float* __restrict__ ml)
{
    __shared__ __align__(16) ushort pbs[2][QB * JB];
    __shared__ float fs2[2][QB];
    __shared__ float lsb[QB];

    const int t    = threadIdx.x;
    const int w    = t >> 6;
    const int lane = t & 63;
    const int lm   = lane & 15;
    const int lg   = lane >> 4;
    const int ib   = w & 3;

    const int n    = blockIdx.x;
    const int b    = (n & 7) >> 1;
    const int half = n & 1;
    const int i0   = (n >> 3) * QB;
    const int J0   = half * (HW / 2);

    const ushort* xb = xbf  + (size_t)b * CCH * HW;
    const float*  mb = mask + (size_t)b * HW;

    bf16x8 qh, ql;
    {
        const size_t qr = ((size_t)(b * HW + i0 + 16 * ib + lm)) * DQK + 8 * lg;
        qh = *(const bf16x8*)(qth + qr);
        ql = *(const bf16x8*)(qtl + qr);
    }
    const float mi = mb[i0 + 16 * ib + lm];
    float mreg = -INFINITY, lreg = 0.f;

    f32x4 acc[2][4];
#pragma unroll
    for (int cf = 0; cf < 2; ++cf)
#pragma unroll
        for (int fi = 0; fi < 4; ++fi) acc[cf][fi] = (f32x4){0.f, 0.f, 0.f, 0.f};

    // preload K-frags for first tile of this half
    bf16x8 kh[4], kl[4];
    if (w < 4) {
#pragma unroll
        for (int mf = 0; mf < 4; ++mf) {
            const size_t kr = ((size_t)(b * HW + J0 + 16 * mf + lm)) * DQK + 8 * lg;
            kh[mf] = *(const bf16x8*)(kth + kr);
            kl[mf] = *(const bf16x8*)(ktl + kr);
        }
    }

    for (int jt = 0; jt < NT2; ++jt) {
        const int j0  = J0 + jt * JB;
        const int buf = jt & 1;

        bf16x8 afr[2][2];
#pragma unroll
        for (int cf = 0; cf < 2; ++cf)
#pragma unroll
            for (int ks = 0; ks < 2; ++ks)
                afr[cf][ks] = *(const bf16x8*)(xb +
                    (size_t)(32 * w + 16 * cf + lm) * HW + j0 + 32 * ks + 8 * lg);

        if (w < 4) {
            f32x4 sc[4];
#pragma unroll
            for (int mf = 0; mf < 4; ++mf) {
                f32x4 z = (f32x4){0.f, 0.f, 0.f, 0.f};
                z = __builtin_amdgcn_mfma_f32_16x16x32_bf16(kh[mf], qh, z, 0, 0, 0);
                z = __builtin_amdgcn_mfma_f32_16x16x32_bf16(kl[mf], qh, z, 0, 0, 0);
                z = __builtin_amdgcn_mfma_f32_16x16x32_bf16(kh[mf], ql, z, 0, 0, 0);
                sc[mf] = z;
            }
            const int jn = (jt + 1 < NT2) ? j0 + JB : j0;
#pragma unroll
            for (int mf = 0; mf < 4; ++mf) {
                const size_t kr = ((size_t)(b * HW + jn + 16 * mf + lm)) * DQK + 8 * lg;
                kh[mf] = *(const bf16x8*)(kth + kr);
                kl[mf] = *(const bf16x8*)(ktl + kr);
            }
            float pm = -INFINITY;
#pragma unroll
            for (int mf = 0; mf < 4; ++mf) {
                float4 mj = *(const float4*)&mb[j0 + 16 * mf + 4 * lg];
#pragma unroll
                for (int r = 0; r < 4; ++r) {
                    float mjr = (r == 0) ? mj.x : (r == 1) ? mj.y : (r == 2) ? mj.z : mj.w;
                    float mm = mi * mjr;
                    float v = (mm == 0.f) ? -INFINITY : sc[mf][r] * mm;
                    sc[mf][r] = v;
                    pm = fmaxf(pm, v);
                }
            }
            pm = fmaxf(pm, __shfl_xor(pm, 16));
            pm = fmaxf(pm, __shfl_xor(pm, 32));
            const float mnew = fmaxf(mreg, pm);
            const float fc   = __expf(mreg - mnew);
            float psum = 0.f;
            const int swz = (lm & 7) << 3;
#pragma unroll
            for (int mf = 0; mf < 4; ++mf) {
                float p0 = __expf(sc[mf][0] - mnew);
                float p1 = __expf(sc[mf][1] - mnew);
                float p2 = __expf(sc[mf][2] - mnew);
                float p3 = __expf(sc[mf][3] - mnew);
                psum += p0 + p1 + p2 + p3;
                *(ushort4*)&pbs[buf][(16 * ib + lm) * JB + ((16 * mf + 4 * lg) ^ swz)] =
                    make_ushort4(f2bf(p0), f2bf(p1), f2bf(p2), f2bf(p3));
            }
            psum += __shfl_xor(psum, 16);
            psum += __shfl_xor(psum, 32);
            lreg = lreg * fc + psum;
            mreg = mnew;
            if (lg == 0) fs2[buf][16 * ib + lm] = fc;
        }
        __syncthreads();

        float fcol[4];
#pragma unroll
        for (int fi = 0; fi < 4; ++fi) fcol[fi] = fs2[buf][16 * fi + lm];
#pragma unroll
        for (int cf = 0; cf < 2; ++cf)
#pragma unroll
            for (int fi = 0; fi < 4; ++fi) acc[cf][fi] *= fcol[fi];

#pragma unroll
        for (int fi = 0; fi < 4; ++fi)
#pragma unroll
            for (int ks = 0; ks < 2; ++ks) {
                bf16x8 bfr = *(const bf16x8*)&pbs[buf][(16 * fi + lm) * JB +
                                ((32 * ks + 8 * lg) ^ ((lm & 7) << 3))];
#pragma unroll
                for (int cf = 0; cf < 2; ++cf)
                    acc[cf][fi] = __builtin_amdgcn_mfma_f32_16x16x32_bf16(
                        afr[cf][ks], bfr, acc[cf][fi], 0, 0, 0);
            }
    }

    // epilogue: per-half (m,l) + normalized partial o, CHANNEL-major (coalesced)
    if (w < 4 && lg == 0) {
        lsb[16 * ib + lm] = lreg;
        ((float2*)ml)[(size_t)half * (4 * HW) + (size_t)b * HW + i0 + 16 * ib + lm] =
            make_float2(mreg, lreg);
    }
    __syncthreads();
    ushort* po = half ? po1 : po0;
    float linv[4];
#pragma unroll
    for (int fi = 0; fi < 4; ++fi) linv[fi] = 1.f / lsb[16 * fi + lm];
#pragma unroll
    for (int cf = 0; cf < 2; ++cf)
#pragma unroll
        for (int fi = 0; fi < 4; ++fi)
#pragma unroll
            for (int r = 0; r < 4; ++r) {
                const int c = 32 * w + 16 * cf + 4 * lg + r;
                po[((size_t)b * CCH + c) * HW + i0 + 16 * fi + lm] =
                    f2bf(acc[cf][fi][r] * linv[fi]);
            }
}

// ---------------------------------------------------------------------------
// K4 (final4): flash-combine + LDS-transpose + MFMA GEMM + residual + LN.
// grid 256 x 512 thr (8 waves). Block = 64 pixels.
// Stage: channel-major po reads (coalesced 128B rows) + combine -> LDS tile
// bt[64 px][256 c] bf16 (32 KB) with XOR swizzle u' = (c>>3)^(px&7) on the
// 16B-unit index (write AND read side — rule 21).
// GEMM: D[o][px] = (Wovh+Wovl) x bt; wave w owns o in [32w,+32).
//   A: Wov rows (global, L2-hot); B: bt rows via swizzled ds_read_b128
//   (bank check: u' spans all 8 16B-groups across lm -> 2-way max = free).
// C-frag: lane holds D[o=32w+16of+4lg+r][px=16pf+lm]. Then residual + LN.
// ---------------------------------------------------------------------------
__global__ __launch_bounds__(512, 2) void final4_kernel(
    const ushort* __restrict__ po0, const ushort* __restrict__ po1,
    const float* __restrict__ ml,
    const ushort* __restrict__ Wovh, const ushort* __restrict__ Wovl,
    const float* __restrict__ bov, const float* __restrict__ x,
    const float* __restrict__ gamma, const float* __restrict__ ln_w,
    const float* __restrict__ ln_b, float* __restrict__ out)
{
    __shared__ __align__(16) ushort bt[64 * 256];   // 32 KB, swizzled
    __shared__ float wc1[64], wc2[64];
    __shared__ float l1[8][4][16], l2[8][4][16];
    __shared__ float lmu[64], lrs[64];

    const int t    = threadIdx.x;
    const int w    = t >> 6;
    const int lane = t & 63;
    const int lm   = lane & 15;
    const int lg   = lane >> 4;
    const int g0   = blockIdx.x * 64;       // global pixel over B*HW
    const int b    = g0 >> 12;
    const int pin0 = g0 & (HW - 1);

    // flash-combine weights for the block's 64 pixels
    if (t < 64) {
        const int P = g0 + t;
        float2 a  = ((const float2*)ml)[P];
        float2 c2 = ((const float2*)ml)[4 * HW + P];
        float M  = fmaxf(a.x, c2.x);
        float e1 = __expf(a.x - M) * a.y;
        float e2 = __expf(c2.x - M) * c2.y;
        float dn = e1 + e2;
        wc1[t] = e1 / dn;
        wc2[t] = e2 / dn;
    }
    __syncthreads();

    // stage: thread (c = rep*64 + t>>3, px0 = 8*(t&7)); wave reads 8 rows
    // of 128 B contiguous (coalesced); swizzled LDS transpose write.
#pragma unroll
    for (int rep = 0; rep < 4; ++rep) {
        const int c   = rep * 64 + (t >> 3);
        const int px0 = (t & 7) * 8;
        const size_t src = ((size_t)b * CCH + c) * HW + pin0 + px0;
        bf16x8 b1 = *(const bf16x8*)(po0 + src);
        bf16x8 b2 = *(const bf16x8*)(po1 + src);
        const int u  = c >> 3;
        const int cl = c & 7;
#pragma unroll
        for (int e = 0; e < 8; ++e) {
            const int px = px0 + e;
            float f = wc1[px] * bf2f((ushort)b1[e]) + wc2[px] * bf2f((ushort)b2[e]);
            bt[px * 256 + ((u ^ (px & 7)) << 3) + cl] = f2bf(f);
        }
    }
    __syncthreads();

    f32x4 acc[2][4];    // [of][pf]
#pragma unroll
    for (int of = 0; of < 2; ++of)
#pragma unroll
        for (int pf = 0; pf < 4; ++pf) acc[of][pf] = (f32x4){0.f, 0.f, 0.f, 0.f};

    for (int ks = 0; ks < 8; ++ks) {
        bf16x8 ah[2], al[2];
#pragma unroll
        for (int of = 0; of < 2; ++of) {
            const size_t r = (size_t)(32 * w + 16 * of + lm) * CCH + 32 * ks + 8 * lg;
            ah[of] = *(const bf16x8*)(Wovh + r);
            al[of] = *(const bf16x8*)(Wovl + r);
        }
        bf16x8 bfr[4];
#pragma unroll
        for (int pf = 0; pf < 4; ++pf) {
            const int px = 16 * pf + lm;
            const int u  = 4 * ks + lg;
            bfr[pf] = *(const bf16x8*)&bt[px * 256 + ((u ^ (px & 7)) << 3)];
        }
#pragma unroll
        for (int of = 0; of < 2; ++of)
#pragma unroll
            for (int pf = 0; pf < 4; ++pf) {
                acc[of][pf] = __builtin_amdgcn_mfma_f32_16x16x32_bf16(
                    ah[of], bfr[pf], acc[of][pf], 0, 0, 0);
                acc[of][pf] = __builtin_amdgcn_mfma_f32_16x16x32_bf16(
                    al[of], bfr[pf], acc[of][pf], 0, 0, 0);
            }
    }

    // residual + per-pixel LN partial sums (v kept in acc)
    const float gam = gamma[0];
    float s1[4] = {0.f, 0.f, 0.f, 0.f}, s2[4] = {0.f, 0.f, 0.f, 0.f};
#pragma unroll
    for (int of = 0; of < 2; ++of)
#pragma unroll
        for (int pf = 0; pf < 4; ++pf)
#pragma unroll
            for (int r = 0; r < 4; ++r) {
                const int o   = 32 * w + 16 * of + 4 * lg + r;
                const int pin = pin0 + 16 * pf + lm;
                float v = fmaf(gam, acc[of][pf][r] + bov[o],
                               x[((size_t)b * CCH + o) * HW + pin]);
                acc[of][pf][r] = v;
                s1[pf] += v;
                s2[pf] = fmaf(v, v, s2[pf]);
            }
#pragma unroll
    for (int pf = 0; pf < 4; ++pf) {
        s1[pf] += __shfl_xor(s1[pf], 16); s1[pf] += __shfl_xor(s1[pf], 32);
        s2[pf] += __shfl_xor(s2[pf], 16); s2[pf] += __shfl_xor(s2[pf], 32);
    }
    if (lg == 0) {
#pragma unroll
        for (int pf = 0; pf < 4; ++pf) {
            l1[w][pf][lm] = s1[pf];
            l2[w][pf][lm] = s2[pf];
        }
    }
    __syncthreads();
    if (t < 64) {
        const int pf = t >> 4, q = t & 15;
        float a = 0.f, qq = 0.f;
#pragma unroll
        for (int ww = 0; ww < 8; ++ww) { a += l1[ww][pf][q]; qq += l2[ww][pf][q]; }
        float mu  = a * (1.f / CCH);
        float var = qq * (1.f / CCH) - mu * mu;
        lmu[t] = mu;
        lrs[t] = 1.f / sqrtf(var + 1e-5f);
    }
    __syncthreads();

#pragma unroll
    for (int of = 0; of < 2; ++of)
#pragma unroll
        for (int pf = 0; pf < 4; ++pf) {
            const float mu = lmu[16 * pf + lm], rs = lrs[16 * pf + lm];
#pragma unroll
            for (int r = 0; r < 4; ++r) {
                const int o   = 32 * w + 16 * of + 4 * lg + r;
                const int pin = pin0 + 16 * pf + lm;
                float v = (acc[of][pf][r] - mu) * rs * ln_w[o] + ln_b[o];
                out[((size_t)b * CCH + o) * HW + pin] = v;
            }
        }
}

// ---------------------------------------------------------------------------
extern "C" void kernel_launch(void* const* d_in, const int* in_sizes, int n_in,
                              void* d_out, int out_size, void* d_ws, size_t ws_size,
                              hipStream_t stream)
{
    const float* x     = (const float*)d_in[0];
    const float* mask  = (const float*)d_in[1];
    const float* Wq    = (const float*)d_in[2];
    const float* bq    = (const float*)d_in[3];
    const float* Wk    = (const float*)d_in[4];
    const float* bk    = (const float*)d_in[5];
    const float* Wv    = (const float*)d_in[6];
    const float* bv    = (const float*)d_in[7];
    const float* Wo    = (const float*)d_in[8];
    const float* bo    = (const float*)d_in[9];
    const float* gamma = (const float*)d_in[10];
    const float* ln_w  = (const float*)d_in[11];
    const float* ln_b  = (const float*)d_in[12];
    float* out = (float*)d_out;

    // ws layout (bytes):
    //   qth/qtl/kth/ktl: 4 x 1MB           @ 0
    //   po0, po1: bf16 [B][C][HW], 8MB ea  @ 4MB
    //   ml: float2 [2][B*HW] = 256KB       @ 20MB
    //   Wovh/Wovl: 128KB each, bov 1KB     @ 20.25MB
    //   xbf: bf16 8MB                      @ ~20.5MB   (total ~28.5MB)
    ushort* qth  = (ushort*)d_ws;
    ushort* qtl  = qth + (size_t)4 * HW * DQK;
    ushort* kth  = qtl + (size_t)4 * HW * DQK;
    ushort* ktl  = kth + (size_t)4 * HW * DQK;
    ushort* po0  = ktl + (size_t)4 * HW * DQK;
    ushort* po1  = po0 + (size_t)4 * HW * CCH;
    float*  ml   = (float*)(po1 + (size_t)4 * HW * CCH);
    ushort* Wovh = (ushort*)(ml + (size_t)2 * 2 * 4 * HW);
    ushort* Wovl = Wovh + CCH * CCH;
    float*  bov  = (float*)(Wovl + CCH * CCH);
    ushort* xbf  = (ushort*)(bov + 256);

    x2bf_kernel<<<4096, 256, 0, stream>>>(x, xbf);
    qkhl_kernel<<<dim3(256, 2), 256, 0, stream>>>(x, Wq, bq, Wk, bk,
                                                  qth, qtl, kth, ktl);
    wov2_kernel<<<256, 256, 0, stream>>>(Wo, Wv, bv, bo, Wovh, Wovl, bov);
    attn4_kernel<<<512, 512, 0, stream>>>(qth, qtl, kth, ktl, xbf, mask,
                                          po0, po1, ml);
    final4_kernel<<<256, 512, 0, stream>>>(po0, po1, ml, Wovh, Wovl, bov, x,
                                           gamma, ln_w, ln_b, out);
}

// Round 12
// 300.783 us; speedup vs baseline: 1.4046x; 1.2938x over previous
//
#include <hip/hip_runtime.h>
#include <math.h>

#define HW 4096
#define CCH 256
#define DQK 32
#define QB 64
#define JB 64
#define NT2 (HW / 2 / JB)   // 32 j-tiles per half-block

typedef __attribute__((ext_vector_type(8))) short bf16x8;
typedef __attribute__((ext_vector_type(4))) float f32x4;

__device__ __forceinline__ ushort f2bf(float f) {
    union { float f; unsigned u; } v; v.f = f;
    unsigned u = v.u;
    unsigned r = u + 0x7fffu + ((u >> 16) & 1u);   // round-to-nearest-even
    return (ushort)(r >> 16);
}
__device__ __forceinline__ float bf2f(ushort h) {
    union { unsigned u; float f; } v; v.u = ((unsigned)h) << 16;
    return v.f;
}

// ---------------------------------------------------------------------------
// K0: x (fp32) -> xbf (bf16), same [B][C][HW] layout.
// ---------------------------------------------------------------------------
__global__ __launch_bounds__(256) void x2bf_kernel(
    const float* __restrict__ x, ushort* __restrict__ xbf)
{
    size_t i = ((size_t)blockIdx.x * 256 + threadIdx.x) * 4;
    float4 v = *(const float4*)(x + i);
    ushort4 o = make_ushort4(f2bf(v.x), f2bf(v.y), f2bf(v.z), f2bf(v.w));
    *(ushort4*)(xbf + i) = o;
}

// ---------------------------------------------------------------------------
// K1: qT/kT in hi+lo bf16, layout [B*HW][32].
// ---------------------------------------------------------------------------
__global__ __launch_bounds__(256) void qkhl_kernel(
    const float* __restrict__ x,
    const float* __restrict__ Wq, const float* __restrict__ bq,
    const float* __restrict__ Wk, const float* __restrict__ bk,
    ushort* __restrict__ qth, ushort* __restrict__ qtl,
    ushort* __restrict__ kth, ushort* __restrict__ ktl)
{
    const float* W    = blockIdx.y ? Wk : Wq;
    const float* bias = blockIdx.y ? bk : bq;
    ushort* outh      = blockIdx.y ? kth : qth;
    ushort* outl      = blockIdx.y ? ktl : qtl;

    const int t  = threadIdx.x;
    const int p  = t & 63;
    const int cq = t >> 6;
    const int g0 = blockIdx.x * 64;
    const int b  = g0 >> 12;
    const int pp = (g0 & (HW - 1)) + p;
    const float* xb = x + (size_t)b * CCH * HW + pp;

    float acc[DQK];
#pragma unroll
    for (int o = 0; o < DQK; ++o) acc[o] = 0.f;

    for (int c0 = 64 * cq; c0 < 64 * cq + 64; c0 += 8) {
        float xv[8];
#pragma unroll
        for (int cc = 0; cc < 8; ++cc) xv[cc] = xb[(size_t)(c0 + cc) * HW];
#pragma unroll
        for (int o = 0; o < DQK; ++o)
#pragma unroll
            for (int cc = 0; cc < 8; ++cc)
                acc[o] = fmaf(W[o * CCH + c0 + cc], xv[cc], acc[o]);
    }

    __shared__ float red[4][64][DQK + 1];
#pragma unroll
    for (int o = 0; o < DQK; ++o) red[cq][p][o] = acc[o];
    __syncthreads();

    const int pr = t & 63;
    const int o8 = t >> 6;
    ushort hv[8], lv[8];
#pragma unroll
    for (int oo = 0; oo < 8; ++oo) {
        const int o = o8 * 8 + oo;
        float s = red[0][pr][o] + red[1][pr][o] + red[2][pr][o] + red[3][pr][o]
                + bias[o];
        ushort h = f2bf(s);
        hv[oo] = h;
        lv[oo] = f2bf(s - bf2f(h));
    }
    const size_t g = (size_t)(g0 + pr) * DQK + o8 * 8;
    *(ushort4*)(outh + g)     = make_ushort4(hv[0], hv[1], hv[2], hv[3]);
    *(ushort4*)(outh + g + 4) = make_ushort4(hv[4], hv[5], hv[6], hv[7]);
    *(ushort4*)(outl + g)     = make_ushort4(lv[0], lv[1], lv[2], lv[3]);
    *(ushort4*)(outl + g + 4) = make_ushort4(lv[4], lv[5], lv[6], lv[7]);
}

// ---------------------------------------------------------------------------
// K2: Wov = Wo x Wv (256x256) emitted as hi/lo bf16; bov = Wo bv + bo (fp32).
// ---------------------------------------------------------------------------
__global__ __launch_bounds__(256) void wov2_kernel(
    const float* __restrict__ Wo, const float* __restrict__ Wv,
    const float* __restrict__ bv, const float* __restrict__ bo,
    ushort* __restrict__ Wovh, ushort* __restrict__ Wovl,
    float* __restrict__ bov)
{
    int o = blockIdx.x;
    int c = threadIdx.x;
    float acc = 0.f;
#pragma unroll 8
    for (int m = 0; m < CCH; ++m)
        acc = fmaf(Wo[o * CCH + m], Wv[m * CCH + c], acc);
    ushort h = f2bf(acc);
    Wovh[o * CCH + c] = h;
    Wovl[o * CCH + c] = f2bf(acc - bf2f(h));

    __shared__ float red[256];
    red[c] = Wo[o * CCH + c] * bv[c];
    __syncthreads();
    for (int s = 128; s > 0; s >>= 1) {
        if (c < s) red[c] += red[c + s];
        __syncthreads();
    }
    if (c == 0) bov[o] = red[0] + bo[o];
}

// ---------------------------------------------------------------------------
// K3: split-j flash attention on x (V/O folded). 512 thr, grid 512.
// __launch_bounds__(512, 2): round 9/10's (512,4) squeezed unified VGPR+AGPR
// to 64+64 -> spill traffic (WRITE_SIZE 400 MB, layout-insensitive). attn3's
// identical body at (512,2) = 84 VGPR, WRITE 16 MB. 84*4 waves = 336 <= 512,
// so 2 blocks/CU residency happens naturally without the forced cap.
// ---------------------------------------------------------------------------
__global__ __launch_bounds__(512, 2) void attn4_kernel(
    const ushort* __restrict__ qth, const ushort* __restrict__ qtl,
    const ushort* __restrict__ kth, const ushort* __restrict__ ktl,
    const ushort* __restrict__ xbf, const float* __restrict__ mask,
    ushort* __restrict__ po0, ushort* __restrict__ po1,
    float* __restrict__ ml)
{
    __shared__ __align__(16) ushort pbs[2][QB * JB];
    __shared__ float fs2[2][QB];
    __shared__ float lsb[QB];

    const int t    = threadIdx.x;
    const int w    = t >> 6;
    const int lane = t & 63;
    const int lm   = lane & 15;
    const int lg   = lane >> 4;
    const int ib   = w & 3;

    const int n    = blockIdx.x;
    const int b    = (n & 7) >> 1;
    const int half = n & 1;
    const int i0   = (n >> 3) * QB;
    const int J0   = half * (HW / 2);

    const ushort* xb = xbf  + (size_t)b * CCH * HW;
    const float*  mb = mask + (size_t)b * HW;

    bf16x8 qh, ql;
    {
        const size_t qr = ((size_t)(b * HW + i0 + 16 * ib + lm)) * DQK + 8 * lg;
        qh = *(const bf16x8*)(qth + qr);
        ql = *(const bf16x8*)(qtl + qr);
    }
    const float mi = mb[i0 + 16 * ib + lm];
    float mreg = -INFINITY, lreg = 0.f;

    f32x4 acc[2][4];
#pragma unroll
    for (int cf = 0; cf < 2; ++cf)
#pragma unroll
        for (int fi = 0; fi < 4; ++fi) acc[cf][fi] = (f32x4){0.f, 0.f, 0.f, 0.f};

    // preload K-frags for first tile of this half
    bf16x8 kh[4], kl[4];
    if (w < 4) {
#pragma unroll
        for (int mf = 0; mf < 4; ++mf) {
            const size_t kr = ((size_t)(b * HW + J0 + 16 * mf + lm)) * DQK + 8 * lg;
            kh[mf] = *(const bf16x8*)(kth + kr);
            kl[mf] = *(const bf16x8*)(ktl + kr);
        }
    }

    for (int jt = 0; jt < NT2; ++jt) {
        const int j0  = J0 + jt * JB;
        const int buf = jt & 1;

        bf16x8 afr[2][2];
#pragma unroll
        for (int cf = 0; cf < 2; ++cf)
#pragma unroll
            for (int ks = 0; ks < 2; ++ks)
                afr[cf][ks] = *(const bf16x8*)(xb +
                    (size_t)(32 * w + 16 * cf + lm) * HW + j0 + 32 * ks + 8 * lg);

        if (w < 4) {
            f32x4 sc[4];
#pragma unroll
            for (int mf = 0; mf < 4; ++mf) {
                f32x4 z = (f32x4){0.f, 0.f, 0.f, 0.f};
                z = __builtin_amdgcn_mfma_f32_16x16x32_bf16(kh[mf], qh, z, 0, 0, 0);
                z = __builtin_amdgcn_mfma_f32_16x16x32_bf16(kl[mf], qh, z, 0, 0, 0);
                z = __builtin_amdgcn_mfma_f32_16x16x32_bf16(kh[mf], ql, z, 0, 0, 0);
                sc[mf] = z;
            }
            const int jn = (jt + 1 < NT2) ? j0 + JB : j0;
#pragma unroll
            for (int mf = 0; mf < 4; ++mf) {
                const size_t kr = ((size_t)(b * HW + jn + 16 * mf + lm)) * DQK + 8 * lg;
                kh[mf] = *(const bf16x8*)(kth + kr);
                kl[mf] = *(const bf16x8*)(ktl + kr);
            }
            float pm = -INFINITY;
#pragma unroll
            for (int mf = 0; mf < 4; ++mf) {
                float4 mj = *(const float4*)&mb[j0 + 16 * mf + 4 * lg];
#pragma unroll
                for (int r = 0; r < 4; ++r) {
                    float mjr = (r == 0) ? mj.x : (r == 1) ? mj.y : (r == 2) ? mj.z : mj.w;
                    float mm = mi * mjr;
                    float v = (mm == 0.f) ? -INFINITY : sc[mf][r] * mm;
                    sc[mf][r] = v;
                    pm = fmaxf(pm, v);
                }
            }
            pm = fmaxf(pm, __shfl_xor(pm, 16));
            pm = fmaxf(pm, __shfl_xor(pm, 32));
            const float mnew = fmaxf(mreg, pm);
            const float fc   = __expf(mreg - mnew);
            float psum = 0.f;
            const int swz = (lm & 7) << 3;
#pragma unroll
            for (int mf = 0; mf < 4; ++mf) {
                float p0 = __expf(sc[mf][0] - mnew);
                float p1 = __expf(sc[mf][1] - mnew);
                float p2 = __expf(sc[mf][2] - mnew);
                float p3 = __expf(sc[mf][3] - mnew);
                psum += p0 + p1 + p2 + p3;
                *(ushort4*)&pbs[buf][(16 * ib + lm) * JB + ((16 * mf + 4 * lg) ^ swz)] =
                    make_ushort4(f2bf(p0), f2bf(p1), f2bf(p2), f2bf(p3));
            }
            psum += __shfl_xor(psum, 16);
            psum += __shfl_xor(psum, 32);
            lreg = lreg * fc + psum;
            mreg = mnew;
            if (lg == 0) fs2[buf][16 * ib + lm] = fc;
        }
        __syncthreads();

        float fcol[4];
#pragma unroll
        for (int fi = 0; fi < 4; ++fi) fcol[fi] = fs2[buf][16 * fi + lm];
#pragma unroll
        for (int cf = 0; cf < 2; ++cf)
#pragma unroll
            for (int fi = 0; fi < 4; ++fi) acc[cf][fi] *= fcol[fi];

#pragma unroll
        for (int fi = 0; fi < 4; ++fi)
#pragma unroll
            for (int ks = 0; ks < 2; ++ks) {
                bf16x8 bfr = *(const bf16x8*)&pbs[buf][(16 * fi + lm) * JB +
                                ((32 * ks + 8 * lg) ^ ((lm & 7) << 3))];
#pragma unroll
                for (int cf = 0; cf < 2; ++cf)
                    acc[cf][fi] = __builtin_amdgcn_mfma_f32_16x16x32_bf16(
                        afr[cf][ks], bfr, acc[cf][fi], 0, 0, 0);
            }
    }

    // epilogue: per-half (m,l) + normalized partial o, CHANNEL-major
    if (w < 4 && lg == 0) {
        lsb[16 * ib + lm] = lreg;
        ((float2*)ml)[(size_t)half * (4 * HW) + (size_t)b * HW + i0 + 16 * ib + lm] =
            make_float2(mreg, lreg);
    }
    __syncthreads();
    ushort* po = half ? po1 : po0;
    float linv[4];
#pragma unroll
    for (int fi = 0; fi < 4; ++fi) linv[fi] = 1.f / lsb[16 * fi + lm];
#pragma unroll
    for (int cf = 0; cf < 2; ++cf)
#pragma unroll
        for (int fi = 0; fi < 4; ++fi)
#pragma unroll
            for (int r = 0; r < 4; ++r) {
                const int c = 32 * w + 16 * cf + 4 * lg + r;
                po[((size_t)b * CCH + c) * HW + i0 + 16 * fi + lm] =
                    f2bf(acc[cf][fi][r] * linv[fi]);
            }
}

// ---------------------------------------------------------------------------
// K4 (final4b): flash-combine + LDS-transpose + MFMA GEMM + residual + LN.
// grid 512 x 256 thr (4 waves). Block = 32 pixels -> 4+ blocks/CU (TLP).
// Stage: channel-major po reads (full 64 B per channel row) + combine ->
// LDS bt[32 px][256+8 c] bf16 (~17 KB; +8 pad = bank-spread, 2-way = free).
// GEMM: D[o][px] = (Wovh+Wovl) x bt; wave w owns o in [64w,+64).
// C-frag: lane holds D[o=64w+16of+4lg+r][px=16pf+lm]. Then residual + LN.
// ---------------------------------------------------------------------------
#define BTS (CCH + 8)
__global__ __launch_bounds__(256, 2) void final4b_kernel(
    const ushort* __restrict__ po0, const ushort* __restrict__ po1,
    const float* __restrict__ ml,
    const ushort* __restrict__ Wovh, const ushort* __restrict__ Wovl,
    const float* __restrict__ bov, const float* __restrict__ x,
    const float* __restrict__ gamma, const float* __restrict__ ln_w,
    const float* __restrict__ ln_b, float* __restrict__ out)
{
    __shared__ __align__(16) ushort bt[32 * BTS];   // ~16.9 KB
    __shared__ float wc1[32], wc2[32];
    __shared__ float l1[4][2][16], l2[4][2][16];
    __shared__ float lmu[2][16], lrs[2][16];

    const int t    = threadIdx.x;
    const int lane = t & 63;
    const int w    = t >> 6;
    const int lm   = lane & 15;
    const int lg   = lane >> 4;
    const int g0   = blockIdx.x * 32;        // global pixel over B*HW
    const int b    = g0 >> 12;
    const int pin0 = g0 & (HW - 1);

    // flash-combine weights for the block's 32 pixels
    if (t < 32) {
        const int P = g0 + t;
        float2 a  = ((const float2*)ml)[P];
        float2 c2 = ((const float2*)ml)[4 * HW + P];
        float M  = fmaxf(a.x, c2.x);
        float e1 = __expf(a.x - M) * a.y;
        float e2 = __expf(c2.x - M) * c2.y;
        float dn = e1 + e2;
        wc1[t] = e1 / dn;
        wc2[t] = e2 / dn;
    }
    __syncthreads();

    // stage: thread (c = rep*64 + t>>2, px0 = 8*(t&3)); 4 lanes cover one
    // channel row's 64 B (full line); combine + transpose into bt[px][c].
#pragma unroll
    for (int rep = 0; rep < 4; ++rep) {
        const int c   = rep * 64 + (t >> 2);
        const int px0 = (t & 3) * 8;
        const size_t src = ((size_t)b * CCH + c) * HW + pin0 + px0;
        bf16x8 b1 = *(const bf16x8*)(po0 + src);
        bf16x8 b2 = *(const bf16x8*)(po1 + src);
#pragma unroll
        for (int e = 0; e < 8; ++e) {
            const int px = px0 + e;
            float f = wc1[px] * bf2f((ushort)b1[e]) + wc2[px] * bf2f((ushort)b2[e]);
            bt[px * BTS + c] = f2bf(f);
        }
    }
    __syncthreads();

    f32x4 acc[4][2];    // [of][pf]
#pragma unroll
    for (int of = 0; of < 4; ++of)
#pragma unroll
        for (int pf = 0; pf < 2; ++pf) acc[of][pf] = (f32x4){0.f, 0.f, 0.f, 0.f};

    for (int ks = 0; ks < 8; ++ks) {
        bf16x8 ah[4], al[4];
#pragma unroll
        for (int of = 0; of < 4; ++of) {
            const size_t r = (size_t)(64 * w + 16 * of + lm) * CCH + 32 * ks + 8 * lg;
            ah[of] = *(const bf16x8*)(Wovh + r);
            al[of] = *(const bf16x8*)(Wovl + r);
        }
        bf16x8 bfr[2];
#pragma unroll
        for (int pf = 0; pf < 2; ++pf) {
            const int px = 16 * pf + lm;
            bfr[pf] = *(const bf16x8*)&bt[px * BTS + 32 * ks + 8 * lg];
        }
#pragma unroll
        for (int of = 0; of < 4; ++of)
#pragma unroll
            for (int pf = 0; pf < 2; ++pf) {
                acc[of][pf] = __builtin_amdgcn_mfma_f32_16x16x32_bf16(
                    ah[of], bfr[pf], acc[of][pf], 0, 0, 0);
                acc[of][pf] = __builtin_amdgcn_mfma_f32_16x16x32_bf16(
                    al[of], bfr[pf], acc[of][pf], 0, 0, 0);
            }
    }

    // residual + per-pixel LN partial sums (v kept in acc)
    const float gam = gamma[0];
    float s1[2] = {0.f, 0.f}, s2[2] = {0.f, 0.f};
#pragma unroll
    for (int of = 0; of < 4; ++of)
#pragma unroll
        for (int pf = 0; pf < 2; ++pf)
#pragma unroll
            for (int r = 0; r < 4; ++r) {
                const int o   = 64 * w + 16 * of + 4 * lg + r;
                const int pin = pin0 + 16 * pf + lm;
                float v = fmaf(gam, acc[of][pf][r] + bov[o],
                               x[((size_t)b * CCH + o) * HW + pin]);
                acc[of][pf][r] = v;
                s1[pf] += v;
                s2[pf] = fmaf(v, v, s2[pf]);
            }
#pragma unroll
    for (int pf = 0; pf < 2; ++pf) {
        s1[pf] += __shfl_xor(s1[pf], 16); s1[pf] += __shfl_xor(s1[pf], 32);
        s2[pf] += __shfl_xor(s2[pf], 16); s2[pf] += __shfl_xor(s2[pf], 32);
    }
    if (lg == 0) {
#pragma unroll
        for (int pf = 0; pf < 2; ++pf) {
            l1[w][pf][lm] = s1[pf];
            l2[w][pf][lm] = s2[pf];
        }
    }
    __syncthreads();
    if (t < 32) {
        const int pf = t >> 4, q = t & 15;
        float a  = l1[0][pf][q] + l1[1][pf][q] + l1[2][pf][q] + l1[3][pf][q];
        float qq = l2[0][pf][q] + l2[1][pf][q] + l2[2][pf][q] + l2[3][pf][q];
        float mu  = a * (1.f / CCH);
        float var = qq * (1.f / CCH) - mu * mu;
        lmu[pf][q] = mu;
        lrs[pf][q] = 1.f / sqrtf(var + 1e-5f);
    }
    __syncthreads();

#pragma unroll
    for (int of = 0; of < 4; ++of)
#pragma unroll
        for (int pf = 0; pf < 2; ++pf) {
            const float mu = lmu[pf][lm], rs = lrs[pf][lm];
#pragma unroll
            for (int r = 0; r < 4; ++r) {
                const int o   = 64 * w + 16 * of + 4 * lg + r;
                const int pin = pin0 + 16 * pf + lm;
                float v = (acc[of][pf][r] - mu) * rs * ln_w[o] + ln_b[o];
                out[((size_t)b * CCH + o) * HW + pin] = v;
            }
        }
}

// ---------------------------------------------------------------------------
extern "C" void kernel_launch(void* const* d_in, const int* in_sizes, int n_in,
                              void* d_out, int out_size, void* d_ws, size_t ws_size,
                              hipStream_t stream)
{
    const float* x     = (const float*)d_in[0];
    const float* mask  = (const float*)d_in[1];
    const float* Wq    = (const float*)d_in[2];
    const float* bq    = (const float*)d_in[3];
    const float* Wk    = (const float*)d_in[4];
    const float* bk    = (const float*)d_in[5];
    const float* Wv    = (const float*)d_in[6];
    const float* bv    = (const float*)d_in[7];
    const float* Wo    = (const float*)d_in[8];
    const float* bo    = (const float*)d_in[9];
    const float* gamma = (const float*)d_in[10];
    const float* ln_w  = (const float*)d_in[11];
    const float* ln_b  = (const float*)d_in[12];
    float* out = (float*)d_out;

    // ws layout (bytes):
    //   qth/qtl/kth/ktl: 4 x 1MB           @ 0
    //   po0, po1: bf16 [B][C][HW], 8MB ea  @ 4MB
    //   ml: float2 [2][B*HW] = 256KB       @ 20MB
    //   Wovh/Wovl: 128KB each, bov 1KB     @ 20.25MB
    //   xbf: bf16 8MB                      @ ~20.5MB   (total ~28.5MB)
    ushort* qth  = (ushort*)d_ws;
    ushort* qtl  = qth + (size_t)4 * HW * DQK;
    ushort* kth  = qtl + (size_t)4 * HW * DQK;
    ushort* ktl  = kth + (size_t)4 * HW * DQK;
    ushort* po0  = ktl + (size_t)4 * HW * DQK;
    ushort* po1  = po0 + (size_t)4 * HW * CCH;
    float*  ml   = (float*)(po1 + (size_t)4 * HW * CCH);
    ushort* Wovh = (ushort*)(ml + (size_t)2 * 2 * 4 * HW);
    ushort* Wovl = Wovh + CCH * CCH;
    float*  bov  = (float*)(Wovl + CCH * CCH);
    ushort* xbf  = (ushort*)(bov + 256);

    x2bf_kernel<<<4096, 256, 0, stream>>>(x, xbf);
    qkhl_kernel<<<dim3(256, 2), 256, 0, stream>>>(x, Wq, bq, Wk, bk,
                                                  qth, qtl, kth, ktl);
    wov2_kernel<<<256, 256, 0, stream>>>(Wo, Wv, bv, bo, Wovh, Wovl, bov);
    attn4_kernel<<<512, 512, 0, stream>>>(qth, qtl, kth, ktl, xbf, mask,
                                          po0, po1, ml);
    final4b_kernel<<<512, 256, 0, stream>>>(po0, po1, ml, Wovh, Wovl, bov, x,
                                            gamma, ln_w, ln_b, out);
}